// Round 5
// baseline (2811.950 us; speedup 1.0000x reference)
//
#include <hip/hip_runtime.h>
#include <math.h>

#define E_DIM 1024
#define H_HEADS 16
#define D_HEAD 64
#define DFF_DIM 4096
#define L_SEQ 2048
#define N_BATCH 2
#define T_TOK (N_BATCH * L_SEQ)

typedef __attribute__((ext_vector_type(8))) __bf16 bf16x8;
typedef __attribute__((ext_vector_type(4))) float f32x4;

__device__ __forceinline__ unsigned short f2bf(float f) {
  union { float f; unsigned int u; } v; v.f = f;
  unsigned int r = v.u + 0x7fffu + ((v.u >> 16) & 1u);
  return (unsigned short)(r >> 16);
}

// async global->LDS, 16B per lane; LDS dest is wave-uniform base + lane*16
__device__ __forceinline__ void gld16(const void* g, void* l) {
  __builtin_amdgcn_global_load_lds(
      (const __attribute__((address_space(1))) unsigned int*)g,
      (__attribute__((address_space(3))) unsigned int*)l, 16, 0, 0);
}

// ---------------- weight convert + transpose: in [K,N] f32 -> out [N,K] bf16 ----
__global__ __launch_bounds__(256) void convert_transpose(
    const float* __restrict__ in, unsigned short* __restrict__ out, int K, int N) {
  __shared__ float tile[32][33];
  int n0 = blockIdx.x * 32, k0 = blockIdx.y * 32;
  int tx = threadIdx.x & 31, ty = threadIdx.x >> 5;  // 32 x 8
#pragma unroll
  for (int i = 0; i < 32; i += 8)
    tile[ty + i][tx] = in[(size_t)(k0 + ty + i) * N + n0 + tx];
  __syncthreads();
#pragma unroll
  for (int i = 0; i < 32; i += 8)
    out[(size_t)(n0 + ty + i) * K + k0 + tx] = f2bf(tile[tx][ty + i]);
}

// ---------------- block reduce (sum pair) over 256 threads ----------------
__device__ __forceinline__ void block_reduce2(float& a, float& b, float* sm, int tid) {
#pragma unroll
  for (int off = 32; off > 0; off >>= 1) {
    a += __shfl_down(a, off);
    b += __shfl_down(b, off);
  }
  int wid = tid >> 6;
  if ((tid & 63) == 0) { sm[wid * 2] = a; sm[wid * 2 + 1] = b; }
  __syncthreads();
  a = sm[0] + sm[2] + sm[4] + sm[6];
  b = sm[1] + sm[3] + sm[5] + sm[7];
}

// ---------------- LN1: x f32 [T,E] -> bf16 [T,E] ----------------
__global__ __launch_bounds__(256) void ln_kernel(
    const float* __restrict__ x, const float* __restrict__ s,
    const float* __restrict__ b, unsigned short* __restrict__ out) {
  int row = blockIdx.x, tid = threadIdx.x;
  __shared__ float sm[8];
  float4 v = ((const float4*)(x + (size_t)row * E_DIM))[tid];
  float sum = v.x + v.y + v.z + v.w;
  float sq = v.x * v.x + v.y * v.y + v.z * v.z + v.w * v.w;
  block_reduce2(sum, sq, sm, tid);
  float mu = sum * (1.0f / E_DIM);
  float var = sq * (1.0f / E_DIM) - mu * mu;
  float rs = rsqrtf(var + 1e-5f);
  float4 sv = ((const float4*)s)[tid];
  float4 bv = ((const float4*)b)[tid];
  ushort4 o4;
  o4.x = f2bf((v.x - mu) * rs * sv.x + bv.x);
  o4.y = f2bf((v.y - mu) * rs * sv.y + bv.y);
  o4.z = f2bf((v.z - mu) * rs * sv.z + bv.z);
  o4.w = f2bf((v.w - mu) * rs * sv.w + bv.w);
  ((ushort4*)(out + (size_t)row * E_DIM))[tid] = o4;
}

// ------ fused: x2 = p0+p1+x+bo ; h2 = LN(LN(x2,s2,b2),sf,bf) -> bf16 --------
__global__ __launch_bounds__(256) void ln2_fused_kernel(
    const float* __restrict__ p0, const float* __restrict__ p1,
    const float* __restrict__ x, const float* __restrict__ bo,
    const float* __restrict__ s2, const float* __restrict__ b2,
    const float* __restrict__ sf, const float* __restrict__ bf_,
    float* __restrict__ x2, unsigned short* __restrict__ out) {
  int row = blockIdx.x, tid = threadIdx.x;
  __shared__ float sm[8];
  float4 a0 = ((const float4*)(p0 + (size_t)row * E_DIM))[tid];
  float4 a1 = ((const float4*)(p1 + (size_t)row * E_DIM))[tid];
  float4 xv = ((const float4*)(x + (size_t)row * E_DIM))[tid];
  float4 bov = ((const float4*)bo)[tid];
  float4 v;
  v.x = a0.x + a1.x + xv.x + bov.x;
  v.y = a0.y + a1.y + xv.y + bov.y;
  v.z = a0.z + a1.z + xv.z + bov.z;
  v.w = a0.w + a1.w + xv.w + bov.w;
  ((float4*)(x2 + (size_t)row * E_DIM))[tid] = v;
  float sum = v.x + v.y + v.z + v.w;
  float sq = v.x * v.x + v.y * v.y + v.z * v.z + v.w * v.w;
  block_reduce2(sum, sq, sm, tid);
  float mu = sum * (1.0f / E_DIM);
  float rs = rsqrtf(sq * (1.0f / E_DIM) - mu * mu + 1e-5f);
  float4 s2v = ((const float4*)s2)[tid];
  float4 b2v = ((const float4*)b2)[tid];
  float y0 = (v.x - mu) * rs * s2v.x + b2v.x;
  float y1 = (v.y - mu) * rs * s2v.y + b2v.y;
  float y2 = (v.z - mu) * rs * s2v.z + b2v.z;
  float y3 = (v.w - mu) * rs * s2v.w + b2v.w;
  float sum2 = y0 + y1 + y2 + y3;
  float sq2 = y0 * y0 + y1 * y1 + y2 * y2 + y3 * y3;
  __syncthreads();
  block_reduce2(sum2, sq2, sm, tid);
  float mu2 = sum2 * (1.0f / E_DIM);
  float rs2 = rsqrtf(sq2 * (1.0f / E_DIM) - mu2 * mu2 + 1e-5f);
  float4 sfv = ((const float4*)sf)[tid];
  float4 bfv = ((const float4*)bf_)[tid];
  ushort4 o4;
  o4.x = f2bf((y0 - mu2) * rs2 * sfv.x + bfv.x);
  o4.y = f2bf((y1 - mu2) * rs2 * sfv.y + bfv.y);
  o4.z = f2bf((y2 - mu2) * rs2 * sfv.z + bfv.z);
  o4.w = f2bf((y3 - mu2) * rs2 * sfv.w + bfv.w);
  ((ushort4*)(out + (size_t)row * E_DIM))[tid] = o4;
}

// ---- FF2 final reduce: out = p0+p1+p2+p3 + resid + bias (all f32) ----------
__global__ __launch_bounds__(256) void add4_kernel(
    const float* __restrict__ p0, const float* __restrict__ p1,
    const float* __restrict__ p2, const float* __restrict__ p3,
    const float* __restrict__ resid, const float* __restrict__ bias,
    float* __restrict__ out) {
  int row = blockIdx.x, tid = threadIdx.x;
  size_t base = (size_t)row * E_DIM;
  float4 a0 = ((const float4*)(p0 + base))[tid];
  float4 a1 = ((const float4*)(p1 + base))[tid];
  float4 a2 = ((const float4*)(p2 + base))[tid];
  float4 a3 = ((const float4*)(p3 + base))[tid];
  float4 rv = ((const float4*)(resid + base))[tid];
  float4 bv = ((const float4*)bias)[tid];
  float4 o;
  o.x = a0.x + a1.x + a2.x + a3.x + rv.x + bv.x;
  o.y = a0.y + a1.y + a2.y + a3.y + rv.y + bv.y;
  o.z = a0.z + a1.z + a2.z + a3.z + rv.z + bv.z;
  o.w = a0.w + a1.w + a2.w + a3.w + rv.w + bv.w;
  ((float4*)(out + base))[tid] = o;
}

// ---------------- GEMM (m97 structure): C[M,N] = A[M,K](bf16) * Bt[N,K]^T ----
// rep: diagnostic amplification — repeats the K-loop (acc reset per rep),
// epilogue once; output identical, dispatch time ≈ rep × true time.
template <int EPI>
__global__ __launch_bounds__(256) void gemm_bt(
    const unsigned short* __restrict__ A, const unsigned short* __restrict__ Bt,
    const float* __restrict__ bias, void* __restrict__ outp,
    int M, int N, int K, int Ks, int rep) {
  __shared__ unsigned short As[128 * 32];
  __shared__ unsigned short Bs[128 * 32];
  int tid = threadIdx.x;
  int lane = tid & 63, wave = tid >> 6;
  int m0 = blockIdx.y * 128, n0 = blockIdx.x * 128;
  int kz = blockIdx.z * Ks;
  int wm = (wave & 1) * 64, wn = (wave >> 1) * 64;
  int lm = lane & 15, lq = lane >> 4;
  int srow = wave * 32 + (lane >> 2);
  int scol = (lane & 3) * 8;
  const unsigned short* Ag = A + (size_t)(m0 + srow) * K + scol;
  const unsigned short* Bg = Bt + (size_t)(n0 + srow) * K + scol;
  unsigned short* AsW = As + wave * 1024;  // 32 rows * 32 shorts
  unsigned short* BsW = Bs + wave * 1024;
  f32x4 acc[4][4];
  for (int rr = 0; rr < rep; rr++) {
#pragma unroll
    for (int i = 0; i < 4; i++)
#pragma unroll
      for (int j = 0; j < 4; j++) {
        f32x4 z = {0.0f, 0.0f, 0.0f, 0.0f};
        acc[i][j] = z;
      }
    for (int k0 = kz; k0 < kz + Ks; k0 += 32) {
      __syncthreads();  // prior iteration's fragment reads done
      gld16(Ag + k0, AsW);
      gld16(Ag + (size_t)16 * K + k0, AsW + 512);
      gld16(Bg + k0, BsW);
      gld16(Bg + (size_t)16 * K + k0, BsW + 512);
      __syncthreads();  // vmcnt drained: tiles staged
      bf16x8 a[4], b[4];
#pragma unroll
      for (int i = 0; i < 4; i++)
        a[i] = *(const bf16x8*)(As + (wm + i * 16 + lm) * 32 + lq * 8);
#pragma unroll
      for (int j = 0; j < 4; j++)
        b[j] = *(const bf16x8*)(Bs + (wn + j * 16 + lm) * 32 + lq * 8);
#pragma unroll
      for (int i = 0; i < 4; i++)
#pragma unroll
        for (int j = 0; j < 4; j++)
          acc[i][j] = __builtin_amdgcn_mfma_f32_16x16x32_bf16(a[i], b[j], acc[i][j], 0, 0, 0);
    }
  }
  float* pout = (EPI == 3) ? ((float*)outp + (size_t)blockIdx.z * M * N) : nullptr;
#pragma unroll
  for (int i = 0; i < 4; i++)
#pragma unroll
    for (int j = 0; j < 4; j++) {
      int row = m0 + wm + i * 16 + lq * 4;
      int col = n0 + wn + j * 16 + lm;
      float bcol = (EPI == 3) ? 0.0f : bias[col];
#pragma unroll
      for (int r = 0; r < 4; r++) {
        float v = acc[i][j][r] + bcol;
        size_t idx = (size_t)(row + r) * N + col;
        if (EPI == 0) {
          ((unsigned short*)outp)[idx] = f2bf(v);
        } else if (EPI == 1) {
          float g = 0.5f * v * (1.0f + erff(v * 0.70710678118f));
          ((unsigned short*)outp)[idx] = f2bf(g);
        } else {
          pout[idx] = v;
        }
      }
    }
}

// ---------------- flash attention (double-buffered, 1 barrier/tile) ----------
// rep: diagnostic amplification — repeats the whole online-softmax pass
// (state reset per rep), epilogue once; output identical.
__global__ __launch_bounds__(256) void attn_kernel(
    const unsigned short* __restrict__ qkv, const int* __restrict__ mask,
    unsigned short* __restrict__ o, int rep) {
  const int bq = blockIdx.x;   // q tile (64 rows)
  const int nh = blockIdx.y;   // n*H + h
  const int h = nh & 15;
  const int tid = threadIdx.x, lane = tid & 63, wave = tid >> 6;
  const int lm = lane & 15, lq = lane >> 4;

  __shared__ unsigned short Ksm[2][64 * 72];
  __shared__ unsigned short Vtm[2][64 * 72];  // [d][key ^ (chunk<<3)]
  __shared__ unsigned short Ps[4][16 * 72];

  const int q_base = bq * 64;
  const int tok0 = (nh >> 4) * L_SEQ;  // batch token offset
  const int qoff = h * 64, koff = E_DIM + h * 64, voff = 2 * E_DIM + h * 64;
  const int* mbase = mask + (size_t)nh * L_SEQ * L_SEQ;

  bf16x8 qf[2];
  {
    int t = tok0 + q_base + wave * 16 + lm;
    const unsigned short* qr = qkv + (size_t)t * (3 * E_DIM) + qoff + lq * 8;
    qf[0] = *(const bf16x8*)(qr);
    qf[1] = *(const bf16x8*)(qr + 32);
  }

  const int qrow = q_base + wave * 16 + lq * 4;
  const int srow = tid >> 3, schunk = tid & 7;
  const size_t TS = 3 * E_DIM;
  const unsigned short* kg = qkv + (size_t)(tok0 + srow) * TS + koff + schunk * 8;
  const unsigned short* vg = qkv + (size_t)(tok0 + srow) * TS + voff + schunk * 8;

  uint4 kreg[2], vreg[2];
  int mreg[16];

  auto load_kv = [&](int kt) {
#pragma unroll
    for (int it = 0; it < 2; it++) {
      size_t toff = (size_t)(kt * 64 + it * 32) * TS;
      kreg[it] = *(const uint4*)(kg + toff);
      vreg[it] = *(const uint4*)(vg + toff);
    }
  };
  auto load_m = [&](int kt) {
#pragma unroll
    for (int nt = 0; nt < 4; nt++)
#pragma unroll
      for (int r = 0; r < 4; r++)
        mreg[nt * 4 + r] =
            mbase[(size_t)(qrow + r) * L_SEQ + kt * 64 + nt * 16 + lm];
  };
  auto store_kv = [&](int buf) {
#pragma unroll
    for (int it = 0; it < 2; it++) {
      int key = srow + it * 32;
      *(uint4*)(Ksm[buf] + key * 72 + schunk * 8) = kreg[it];
      const unsigned short* vs = (const unsigned short*)&vreg[it];
      int kcol = key ^ (schunk << 3);  // swizzle: spreads banks
#pragma unroll
      for (int jj = 0; jj < 8; jj++)
        Vtm[buf][(schunk * 8 + jj) * 72 + kcol] = vs[jj];
    }
  };

  float m_run[4], l_run[4];
  f32x4 oacc[4];
  const int NT = L_SEQ / 64;

  for (int rr = 0; rr < rep; rr++) {
#pragma unroll
    for (int r = 0; r < 4; r++) { m_run[r] = -1e30f; l_run[r] = 0.0f; }
#pragma unroll
    for (int j = 0; j < 4; j++) {
      f32x4 z = {0.0f, 0.0f, 0.0f, 0.0f};
      oacc[j] = z;
    }

    // prologue: stage tile 0
    load_kv(0);
    load_m(0);
    store_kv(0);
    __syncthreads();

    int cur = 0;
    for (int kt = 0; kt < NT; kt++) {
      // ---- S = Q K^T ----
      f32x4 s[4];
      __builtin_amdgcn_s_setprio(1);
#pragma unroll
      for (int nt = 0; nt < 4; nt++) {
        bf16x8 kb0 = *(const bf16x8*)(Ksm[cur] + (nt * 16 + lm) * 72 + lq * 8);
        bf16x8 kb1 = *(const bf16x8*)(Ksm[cur] + (nt * 16 + lm) * 72 + 32 + lq * 8);
        f32x4 acc = {};
        acc = __builtin_amdgcn_mfma_f32_16x16x32_bf16(qf[0], kb0, acc, 0, 0, 0);
        acc = __builtin_amdgcn_mfma_f32_16x16x32_bf16(qf[1], kb1, acc, 0, 0, 0);
        s[nt] = acc;
      }
      __builtin_amdgcn_s_setprio(0);

      // ---- mask with prefetched regs ----
#pragma unroll
      for (int nt = 0; nt < 4; nt++)
#pragma unroll
        for (int r = 0; r < 4; r++) {
          float v = s[nt][r] * 0.125f;  // D^-0.5
          s[nt][r] = mreg[nt * 4 + r] ? -1e30f : v;
        }

      // ---- issue next tile's global loads ----
      int ktn = (kt + 1 < NT) ? kt + 1 : kt;
      load_kv(ktn);
      load_m(ktn);

      // ---- online softmax ----
      float alpha[4], rsum[4];
#pragma unroll
      for (int r = 0; r < 4; r++) {
        float v = fmaxf(fmaxf(s[0][r], s[1][r]), fmaxf(s[2][r], s[3][r]));
#pragma unroll
        for (int mo = 1; mo < 16; mo <<= 1) v = fmaxf(v, __shfl_xor(v, mo));
        float mn = fmaxf(m_run[r], v);
        alpha[r] = __expf(m_run[r] - mn);
        m_run[r] = mn;
        rsum[r] = 0.0f;
      }
      unsigned short* pw = Ps[wave];
#pragma unroll
      for (int nt = 0; nt < 4; nt++)
#pragma unroll
        for (int r = 0; r < 4; r++) {
          float p = __expf(s[nt][r] - m_run[r]);
          rsum[r] += p;
          pw[(lq * 4 + r) * 72 + nt * 16 + lm] = f2bf(p);
        }
#pragma unroll
      for (int r = 0; r < 4; r++) {
        float v = rsum[r];
#pragma unroll
        for (int mo = 1; mo < 16; mo <<= 1) v += __shfl_xor(v, mo);
        l_run[r] = l_run[r] * alpha[r] + v;
      }
#pragma unroll
      for (int j = 0; j < 4; j++)
#pragma unroll
        for (int r = 0; r < 4; r++) oacc[j][r] *= alpha[r];

      asm volatile("s_waitcnt lgkmcnt(0)" ::: "memory");
      __builtin_amdgcn_sched_barrier(0);

      // ---- O += P V ----
      __builtin_amdgcn_s_setprio(1);
#pragma unroll
      for (int c = 0; c < 2; c++) {
        bf16x8 pa = *(const bf16x8*)(pw + lm * 72 + c * 32 + lq * 8);
#pragma unroll
        for (int j = 0; j < 4; j++) {
          int d = j * 16 + lm;
          int kblk = (c * 4 + lq) ^ ((d >> 3) & 7);  // undo staging swizzle
          bf16x8 vb = *(const bf16x8*)(Vtm[cur] + d * 72 + kblk * 8);
          oacc[j] = __builtin_amdgcn_mfma_f32_16x16x32_bf16(pa, vb, oacc[j], 0, 0, 0);
        }
      }
      __builtin_amdgcn_s_setprio(0);

      // ---- stage next tile, one barrier ----
      store_kv(cur ^ 1);
      __syncthreads();
      cur ^= 1;
    }
  }

  // epilogue
#pragma unroll
  for (int r = 0; r < 4; r++) {
    float inv_l = 1.0f / l_run[r];
    int t = tok0 + qrow + r;
#pragma unroll
    for (int j = 0; j < 4; j++)
      o[(size_t)t * E_DIM + h * 64 + j * 16 + lm] = f2bf(oacc[j][r] * inv_l);
  }
}

extern "C" void kernel_launch(void* const* d_in, const int* in_sizes, int n_in,
                              void* d_out, int out_size, void* d_ws, size_t ws_size,
                              hipStream_t stream) {
  const float* x = (const float*)d_in[0];
  const int* mask = (const int*)d_in[1];
  const float* ln1_s = (const float*)d_in[2];
  const float* ln1_b = (const float*)d_in[3];
  const float* Wqkv = (const float*)d_in[4];
  const float* bqkv = (const float*)d_in[5];
  const float* Wo = (const float*)d_in[6];
  const float* bo = (const float*)d_in[7];
  const float* ln2_s = (const float*)d_in[8];
  const float* ln2_b = (const float*)d_in[9];
  const float* lnf_s = (const float*)d_in[10];
  const float* lnf_b = (const float*)d_in[11];
  const float* W1 = (const float*)d_in[12];
  const float* b1 = (const float*)d_in[13];
  const float* W2 = (const float*)d_in[14];
  const float* b2 = (const float*)d_in[15];

  size_t off = 0;
  auto alloc = [&](size_t bytes) {
    void* p = (char*)d_ws + off;
    off += (bytes + 255) & ~(size_t)255;
    return p;
  };
  unsigned short* WqkvT = (unsigned short*)alloc((size_t)3072 * 1024 * 2);
  unsigned short* WoT = (unsigned short*)alloc((size_t)1024 * 1024 * 2);
  unsigned short* W1T = (unsigned short*)alloc((size_t)4096 * 1024 * 2);
  unsigned short* W2T = (unsigned short*)alloc((size_t)1024 * 4096 * 2);
  unsigned short* h1 = (unsigned short*)alloc((size_t)T_TOK * E_DIM * 2);
  unsigned short* qkvb = (unsigned short*)alloc((size_t)T_TOK * 3 * E_DIM * 2);
  unsigned short* ob = (unsigned short*)alloc((size_t)T_TOK * E_DIM * 2);
  float* x2 = (float*)alloc((size_t)T_TOK * E_DIM * 4);
  unsigned short* h2 = (unsigned short*)alloc((size_t)T_TOK * E_DIM * 2);
  unsigned short* g1 = (unsigned short*)alloc((size_t)T_TOK * DFF_DIM * 2);
  float* part = (float*)alloc((size_t)4 * T_TOK * E_DIM * 4);  // 4 K-slices
  const size_t PSTRIDE = (size_t)T_TOK * E_DIM;

  // weight prep
  convert_transpose<<<dim3(3072 / 32, 1024 / 32), 256, 0, stream>>>(Wqkv, WqkvT, 1024, 3072);
  convert_transpose<<<dim3(1024 / 32, 1024 / 32), 256, 0, stream>>>(Wo, WoT, 1024, 1024);
  convert_transpose<<<dim3(4096 / 32, 1024 / 32), 256, 0, stream>>>(W1, W1T, 1024, 4096);
  convert_transpose<<<dim3(1024 / 32, 4096 / 32), 256, 0, stream>>>(W2, W2T, 4096, 1024);
  // LN1
  ln_kernel<<<T_TOK, 256, 0, stream>>>(x, ln1_s, ln1_b, h1);
  // QKV  [AMPLIFIED x12 for profiling visibility]
  gemm_bt<0><<<dim3(3072 / 128, T_TOK / 128, 1), 256, 0, stream>>>(
      h1, WqkvT, bqkv, qkvb, T_TOK, 3072, 1024, 1024, 12);
  // attention  [AMPLIFIED x6]
  attn_kernel<<<dim3(L_SEQ / 64, N_BATCH * H_HEADS), 256, 0, stream>>>(
      qkvb, mask, ob, 6);
  // Wo split-K=2 -> part[0],part[1]  (not amplified)
  gemm_bt<3><<<dim3(1024 / 128, T_TOK / 128, 2), 256, 0, stream>>>(
      ob, WoT, nullptr, part, T_TOK, 1024, 1024, 512, 1);
  // x2 = p0+p1+x+bo ; h2 = LN(LN(x2))
  ln2_fused_kernel<<<T_TOK, 256, 0, stream>>>(
      part, part + PSTRIDE, x, bo, ln2_s, ln2_b, lnf_s, lnf_b, x2, h2);
  // FF1 + gelu  [AMPLIFIED x8]
  gemm_bt<1><<<dim3(DFF_DIM / 128, T_TOK / 128, 1), 256, 0, stream>>>(
      h2, W1T, b1, g1, T_TOK, DFF_DIM, 1024, 1024, 8);
  // FF2 split-K=4 -> part[0..3]  [AMPLIFIED x8]
  gemm_bt<3><<<dim3(1024 / 128, T_TOK / 128, 4), 256, 0, stream>>>(
      g1, W2T, nullptr, part, T_TOK, 1024, 4096, 1024, 8);
  // out = p0+p1+p2+p3 + x2 + b2
  add4_kernel<<<T_TOK, 256, 0, stream>>>(
      part, part + PSTRIDE, part + 2 * PSTRIDE, part + 3 * PSTRIDE,
      x2, b2, (float*)d_out);

  (void)in_sizes; (void)n_in; (void)out_size; (void)ws_size;
}

// Round 6
// 1071.852 us; speedup vs baseline: 2.6234x; 2.6234x over previous
//
#include <hip/hip_runtime.h>
#include <math.h>

#define E_DIM 1024
#define H_HEADS 16
#define D_HEAD 64
#define DFF_DIM 4096
#define L_SEQ 2048
#define N_BATCH 2
#define T_TOK (N_BATCH * L_SEQ)

typedef __attribute__((ext_vector_type(8))) __bf16 bf16x8;
typedef __attribute__((ext_vector_type(4))) float f32x4;

__device__ __forceinline__ unsigned short f2bf(float f) {
  union { float f; unsigned int u; } v; v.f = f;
  unsigned int r = v.u + 0x7fffu + ((v.u >> 16) & 1u);
  return (unsigned short)(r >> 16);
}

// async global->LDS, 16B per lane; LDS dest is wave-uniform base + lane*16;
// global source address is PER-LANE (swizzles live on the global side).
__device__ __forceinline__ void gld16(const void* g, void* l) {
  __builtin_amdgcn_global_load_lds(
      (const __attribute__((address_space(1))) unsigned int*)g,
      (__attribute__((address_space(3))) unsigned int*)l, 16, 0, 0);
}

// ---------------- weight convert + transpose: in [K,N] f32 -> out [N,K] bf16 ----
__global__ __launch_bounds__(256) void convert_transpose(
    const float* __restrict__ in, unsigned short* __restrict__ out, int K, int N) {
  __shared__ float tile[32][33];
  int n0 = blockIdx.x * 32, k0 = blockIdx.y * 32;
  int tx = threadIdx.x & 31, ty = threadIdx.x >> 5;  // 32 x 8
#pragma unroll
  for (int i = 0; i < 32; i += 8)
    tile[ty + i][tx] = in[(size_t)(k0 + ty + i) * N + n0 + tx];
  __syncthreads();
#pragma unroll
  for (int i = 0; i < 32; i += 8)
    out[(size_t)(n0 + ty + i) * K + k0 + tx] = f2bf(tile[tx][ty + i]);
}

// ---- V transpose: qkv bf16 [T,3E] V-part -> vtg [nh=32][d=64][L] bf16 -------
__global__ __launch_bounds__(256) void v_transpose(
    const unsigned short* __restrict__ qkv, unsigned short* __restrict__ vtg) {
  __shared__ unsigned short t[64][72];
  int kb = blockIdx.x * 64;
  int nh = blockIdx.y, n = nh >> 4, h = nh & 15;
  int tid = threadIdx.x;
  int r = tid >> 3, ch = tid & 7;
  const size_t TS = 3 * E_DIM;
  const size_t voff = 2 * E_DIM + h * 64;
#pragma unroll
  for (int it = 0; it < 2; it++) {
    int row = r + it * 32;  // token within tile
    uint4 v = *(const uint4*)(qkv + (size_t)(n * L_SEQ + kb + row) * TS + voff + ch * 8);
    *(uint4*)(&t[row][ch * 8]) = v;
  }
  __syncthreads();
#pragma unroll
  for (int it = 0; it < 2; it++) {
    int d = r + it * 32;
    unsigned short tmp[8];
#pragma unroll
    for (int s = 0; s < 8; s++) tmp[s] = t[ch * 8 + s][d];
    *(uint4*)(vtg + ((size_t)nh * 64 + d) * L_SEQ + kb + ch * 8) = *(uint4*)tmp;
  }
}

// ---------------- block reduce (sum pair) over 256 threads ----------------
__device__ __forceinline__ void block_reduce2(float& a, float& b, float* sm, int tid) {
#pragma unroll
  for (int off = 32; off > 0; off >>= 1) {
    a += __shfl_down(a, off);
    b += __shfl_down(b, off);
  }
  int wid = tid >> 6;
  if ((tid & 63) == 0) { sm[wid * 2] = a; sm[wid * 2 + 1] = b; }
  __syncthreads();
  a = sm[0] + sm[2] + sm[4] + sm[6];
  b = sm[1] + sm[3] + sm[5] + sm[7];
}

// ---------------- LN1: x f32 [T,E] -> bf16 [T,E] ----------------
__global__ __launch_bounds__(256) void ln_kernel(
    const float* __restrict__ x, const float* __restrict__ s,
    const float* __restrict__ b, unsigned short* __restrict__ out) {
  int row = blockIdx.x, tid = threadIdx.x;
  __shared__ float sm[8];
  float4 v = ((const float4*)(x + (size_t)row * E_DIM))[tid];
  float sum = v.x + v.y + v.z + v.w;
  float sq = v.x * v.x + v.y * v.y + v.z * v.z + v.w * v.w;
  block_reduce2(sum, sq, sm, tid);
  float mu = sum * (1.0f / E_DIM);
  float var = sq * (1.0f / E_DIM) - mu * mu;
  float rs = rsqrtf(var + 1e-5f);
  float4 sv = ((const float4*)s)[tid];
  float4 bv = ((const float4*)b)[tid];
  ushort4 o4;
  o4.x = f2bf((v.x - mu) * rs * sv.x + bv.x);
  o4.y = f2bf((v.y - mu) * rs * sv.y + bv.y);
  o4.z = f2bf((v.z - mu) * rs * sv.z + bv.z);
  o4.w = f2bf((v.w - mu) * rs * sv.w + bv.w);
  ((ushort4*)(out + (size_t)row * E_DIM))[tid] = o4;
}

// ------ fused: x2 = p0+p1+x+bo ; h2 = LN(LN(x2,s2,b2),sf,bf) -> bf16 --------
__global__ __launch_bounds__(256) void ln2_fused_kernel(
    const float* __restrict__ p0, const float* __restrict__ p1,
    const float* __restrict__ x, const float* __restrict__ bo,
    const float* __restrict__ s2, const float* __restrict__ b2,
    const float* __restrict__ sf, const float* __restrict__ bf_,
    float* __restrict__ x2, unsigned short* __restrict__ out) {
  int row = blockIdx.x, tid = threadIdx.x;
  __shared__ float sm[8];
  float4 a0 = ((const float4*)(p0 + (size_t)row * E_DIM))[tid];
  float4 a1 = ((const float4*)(p1 + (size_t)row * E_DIM))[tid];
  float4 xv = ((const float4*)(x + (size_t)row * E_DIM))[tid];
  float4 bov = ((const float4*)bo)[tid];
  float4 v;
  v.x = a0.x + a1.x + xv.x + bov.x;
  v.y = a0.y + a1.y + xv.y + bov.y;
  v.z = a0.z + a1.z + xv.z + bov.z;
  v.w = a0.w + a1.w + xv.w + bov.w;
  ((float4*)(x2 + (size_t)row * E_DIM))[tid] = v;
  float sum = v.x + v.y + v.z + v.w;
  float sq = v.x * v.x + v.y * v.y + v.z * v.z + v.w * v.w;
  block_reduce2(sum, sq, sm, tid);
  float mu = sum * (1.0f / E_DIM);
  float rs = rsqrtf(sq * (1.0f / E_DIM) - mu * mu + 1e-5f);
  float4 s2v = ((const float4*)s2)[tid];
  float4 b2v = ((const float4*)b2)[tid];
  float y0 = (v.x - mu) * rs * s2v.x + b2v.x;
  float y1 = (v.y - mu) * rs * s2v.y + b2v.y;
  float y2 = (v.z - mu) * rs * s2v.z + b2v.z;
  float y3 = (v.w - mu) * rs * s2v.w + b2v.w;
  float sum2 = y0 + y1 + y2 + y3;
  float sq2 = y0 * y0 + y1 * y1 + y2 * y2 + y3 * y3;
  __syncthreads();
  block_reduce2(sum2, sq2, sm, tid);
  float mu2 = sum2 * (1.0f / E_DIM);
  float rs2 = rsqrtf(sq2 * (1.0f / E_DIM) - mu2 * mu2 + 1e-5f);
  float4 sfv = ((const float4*)sf)[tid];
  float4 bfv = ((const float4*)bf_)[tid];
  ushort4 o4;
  o4.x = f2bf((y0 - mu2) * rs2 * sfv.x + bfv.x);
  o4.y = f2bf((y1 - mu2) * rs2 * sfv.y + bfv.y);
  o4.z = f2bf((y2 - mu2) * rs2 * sfv.z + bfv.z);
  o4.w = f2bf((y3 - mu2) * rs2 * sfv.w + bfv.w);
  ((ushort4*)(out + (size_t)row * E_DIM))[tid] = o4;
}

// ---- FF2 final reduce: out = p0+p1+p2+p3 + resid + bias (all f32) ----------
__global__ __launch_bounds__(256) void add4_kernel(
    const float* __restrict__ p0, const float* __restrict__ p1,
    const float* __restrict__ p2, const float* __restrict__ p3,
    const float* __restrict__ resid, const float* __restrict__ bias,
    float* __restrict__ out) {
  int row = blockIdx.x, tid = threadIdx.x;
  size_t base = (size_t)row * E_DIM;
  float4 a0 = ((const float4*)(p0 + base))[tid];
  float4 a1 = ((const float4*)(p1 + base))[tid];
  float4 a2 = ((const float4*)(p2 + base))[tid];
  float4 a3 = ((const float4*)(p3 + base))[tid];
  float4 rv = ((const float4*)(resid + base))[tid];
  float4 bv = ((const float4*)bias)[tid];
  float4 o;
  o.x = a0.x + a1.x + a2.x + a3.x + rv.x + bv.x;
  o.y = a0.y + a1.y + a2.y + a3.y + rv.y + bv.y;
  o.z = a0.z + a1.z + a2.z + a3.z + rv.z + bv.z;
  o.w = a0.w + a1.w + a2.w + a3.w + rv.w + bv.w;
  ((float4*)(out + base))[tid] = o;
}

// ---------------- GEMM (m97 structure): C[M,N] = A[M,K](bf16) * Bt[N,K]^T ----
// EPI 0: store bf16 (+bias); 1: gelu->bf16 (+bias); 3: f32 partial (split-K).
template <int EPI>
__global__ __launch_bounds__(256) void gemm_bt(
    const unsigned short* __restrict__ A, const unsigned short* __restrict__ Bt,
    const float* __restrict__ bias, void* __restrict__ outp,
    int M, int N, int K, int Ks) {
  __shared__ unsigned short As[128 * 32];
  __shared__ unsigned short Bs[128 * 32];
  int tid = threadIdx.x;
  int lane = tid & 63, wave = tid >> 6;
  int m0 = blockIdx.y * 128, n0 = blockIdx.x * 128;
  int kz = blockIdx.z * Ks;
  int wm = (wave & 1) * 64, wn = (wave >> 1) * 64;
  int lm = lane & 15, lq = lane >> 4;
  int srow = wave * 32 + (lane >> 2);
  int scol = (lane & 3) * 8;
  const unsigned short* Ag = A + (size_t)(m0 + srow) * K + scol;
  const unsigned short* Bg = Bt + (size_t)(n0 + srow) * K + scol;
  unsigned short* AsW = As + wave * 1024;
  unsigned short* BsW = Bs + wave * 1024;
  f32x4 acc[4][4] = {};
  for (int k0 = kz; k0 < kz + Ks; k0 += 32) {
    __syncthreads();
    gld16(Ag + k0, AsW);
    gld16(Ag + (size_t)16 * K + k0, AsW + 512);
    gld16(Bg + k0, BsW);
    gld16(Bg + (size_t)16 * K + k0, BsW + 512);
    __syncthreads();
    bf16x8 a[4], b[4];
#pragma unroll
    for (int i = 0; i < 4; i++)
      a[i] = *(const bf16x8*)(As + (wm + i * 16 + lm) * 32 + lq * 8);
#pragma unroll
    for (int j = 0; j < 4; j++)
      b[j] = *(const bf16x8*)(Bs + (wn + j * 16 + lm) * 32 + lq * 8);
#pragma unroll
    for (int i = 0; i < 4; i++)
#pragma unroll
      for (int j = 0; j < 4; j++)
        acc[i][j] = __builtin_amdgcn_mfma_f32_16x16x32_bf16(a[i], b[j], acc[i][j], 0, 0, 0);
  }
  float* pout = (EPI == 3) ? ((float*)outp + (size_t)blockIdx.z * M * N) : nullptr;
#pragma unroll
  for (int i = 0; i < 4; i++)
#pragma unroll
    for (int j = 0; j < 4; j++) {
      int row = m0 + wm + i * 16 + lq * 4;
      int col = n0 + wn + j * 16 + lm;
      float bcol = (EPI == 3) ? 0.0f : bias[col];
#pragma unroll
      for (int r = 0; r < 4; r++) {
        float v = acc[i][j][r] + bcol;
        size_t idx = (size_t)(row + r) * N + col;
        if (EPI == 0) {
          ((unsigned short*)outp)[idx] = f2bf(v);
        } else if (EPI == 1) {
          float g = 0.5f * v * (1.0f + erff(v * 0.70710678118f));
          ((unsigned short*)outp)[idx] = f2bf(g);
        } else {
          pout[idx] = v;
        }
      }
    }
}

// ---------------- flash attention v3 ----------------
// gld16-staged K and pre-transposed V, XOR-swizzled linear LDS tiles.
// Per tile: issue next tile's gld16 -> QK^T(cur) -> mask -> prefetch next
// mask -> softmax -> P store (swizzled) -> lgkm drain -> PV(cur) -> barrier.
// LDS 40 KB -> 4 blocks/CU.
__global__ __launch_bounds__(256) void attn_kernel(
    const unsigned short* __restrict__ qkv,
    const unsigned short* __restrict__ vtg,
    const int* __restrict__ mask,
    unsigned short* __restrict__ o) {
  const int bq = blockIdx.x;   // q tile (64 rows)
  const int nh = blockIdx.y;   // n*H + h
  const int h = nh & 15;
  const int tid = threadIdx.x, lane = tid & 63, wave = tid >> 6;
  const int lm = lane & 15, lq = lane >> 4, lm7 = lm & 7;

  __shared__ unsigned short Kb[2][64 * 64];   // [key][chunk^ (key&7)]
  __shared__ unsigned short Vb[2][64 * 64];   // [d][kchunk ^ (d&7)]
  __shared__ unsigned short Ps[4][16 * 64];   // [q][kchunk ^ (q&7)]

  const int q_base = bq * 64;
  const int tok0 = (nh >> 4) * L_SEQ;
  const int qoff = h * 64, koff = E_DIM + h * 64;
  const int* mbase = mask + (size_t)nh * L_SEQ * L_SEQ;
  const size_t TS = 3 * E_DIM;

  // Q fragments
  bf16x8 qf[2];
  {
    int t = tok0 + q_base + wave * 16 + lm;
    const unsigned short* qr = qkv + (size_t)t * TS + qoff + lq * 8;
    qf[0] = *(const bf16x8*)(qr);
    qf[1] = *(const bf16x8*)(qr + 32);
  }

  const int qrow = q_base + wave * 16 + lq * 4;
  // staging lane geometry: call covers 8 rows x 128B; lane -> row lrow, chunk
  // (lane&7) XOR'd with row&7 (== lrow) on the GLOBAL side, LDS stays linear.
  const int lrow = lane >> 3;
  const int xch = ((lane & 7) ^ lrow) * 8;
  const unsigned short* kgb = qkv + koff + xch;
  const unsigned short* vgb = vtg + (size_t)nh * 64 * L_SEQ + xch;

  auto STAGE = [&](int buf, int kt) {
    int kb = kt * 64;
#pragma unroll
    for (int cc = 0; cc < 2; cc++) {
      int c = wave * 2 + cc;
      int row = c * 8 + lrow;
      gld16(kgb + (size_t)(tok0 + kb + row) * TS, Kb[buf] + c * 512);
      gld16(vgb + (size_t)row * L_SEQ + kb, Vb[buf] + c * 512);
    }
  };

  int mreg[16];
  auto load_m = [&](int kt) {
#pragma unroll
    for (int nt = 0; nt < 4; nt++)
#pragma unroll
      for (int r = 0; r < 4; r++)
        mreg[nt * 4 + r] =
            mbase[(size_t)(qrow + r) * L_SEQ + kt * 64 + nt * 16 + lm];
  };

  float m_run[4], l_run[4];
  f32x4 oacc[4] = {};
#pragma unroll
  for (int r = 0; r < 4; r++) { m_run[r] = -1e30f; l_run[r] = 0.0f; }

  // prologue
  STAGE(0, 0);
  load_m(0);
  __syncthreads();  // drains vmcnt -> tile 0 staged

  int cur = 0;
  const int NT = L_SEQ / 64;
  for (int kt = 0; kt < NT; kt++) {
    // issue next tile's DMA first: whole tile of compute hides it
    if (kt + 1 < NT) STAGE(cur ^ 1, kt + 1);

    // ---- S = Q K^T ----
    f32x4 s[4];
    __builtin_amdgcn_s_setprio(1);
#pragma unroll
    for (int nt = 0; nt < 4; nt++) {
      int kidx = (nt * 16 + lm) * 64 + ((lq ^ lm7) << 3);
      bf16x8 kb0 = *(const bf16x8*)(Kb[cur] + kidx);
      bf16x8 kb1 = *(const bf16x8*)(Kb[cur] + (kidx ^ 32));
      f32x4 acc = {};
      acc = __builtin_amdgcn_mfma_f32_16x16x32_bf16(qf[0], kb0, acc, 0, 0, 0);
      acc = __builtin_amdgcn_mfma_f32_16x16x32_bf16(qf[1], kb1, acc, 0, 0, 0);
      s[nt] = acc;
    }
    __builtin_amdgcn_s_setprio(0);

    // ---- mask (prefetched regs) ----
#pragma unroll
    for (int nt = 0; nt < 4; nt++)
#pragma unroll
      for (int r = 0; r < 4; r++) {
        float v = s[nt][r] * 0.125f;  // D^-0.5
        s[nt][r] = mreg[nt * 4 + r] ? -1e30f : v;
      }
    // prefetch next tile's mask (latency hides under softmax+PV)
    load_m((kt + 1 < NT) ? kt + 1 : kt);

    // ---- online softmax ----
    float alpha[4], rsum[4];
#pragma unroll
    for (int r = 0; r < 4; r++) {
      float v = fmaxf(fmaxf(s[0][r], s[1][r]), fmaxf(s[2][r], s[3][r]));
#pragma unroll
      for (int mo = 1; mo < 16; mo <<= 1) v = fmaxf(v, __shfl_xor(v, mo));
      float mn = fmaxf(m_run[r], v);
      alpha[r] = __expf(m_run[r] - mn);
      m_run[r] = mn;
      rsum[r] = 0.0f;
    }
    unsigned short* pw = Ps[wave];
#pragma unroll
    for (int r = 0; r < 4; r++) {
      int prow = lq * 4 + r;
      int pbase = prow * 64 + lm7;
      int p7 = prow & 7;
#pragma unroll
      for (int nt = 0; nt < 4; nt++) {
        float p = __expf(s[nt][r] - m_run[r]);
        rsum[r] += p;
        pw[pbase + ((((nt << 1) | (lm >> 3)) ^ p7) << 3)] = f2bf(p);
      }
    }
#pragma unroll
    for (int r = 0; r < 4; r++) {
      float v = rsum[r];
#pragma unroll
      for (int mo = 1; mo < 16; mo <<= 1) v += __shfl_xor(v, mo);
      l_run[r] = l_run[r] * alpha[r] + v;
    }
#pragma unroll
    for (int j = 0; j < 4; j++)
#pragma unroll
      for (int r = 0; r < 4; r++) oacc[j][r] *= alpha[r];

    // P write -> P read is cross-lane via LDS: explicit drain (rule #18)
    asm volatile("s_waitcnt lgkmcnt(0)" ::: "memory");
    __builtin_amdgcn_sched_barrier(0);

    // ---- O += P V ----
    __builtin_amdgcn_s_setprio(1);
#pragma unroll
    for (int c = 0; c < 2; c++) {
      int pc = ((((c << 2) | lq)) ^ lm7) << 3;  // same swizzle for P and Vt
      bf16x8 pa = *(const bf16x8*)(pw + lm * 64 + pc);
#pragma unroll
      for (int j = 0; j < 4; j++) {
        bf16x8 vb = *(const bf16x8*)(Vb[cur] + (j * 16 + lm) * 64 + pc);
        oacc[j] = __builtin_amdgcn_mfma_f32_16x16x32_bf16(pa, vb, oacc[j], 0, 0, 0);
      }
    }
    __builtin_amdgcn_s_setprio(0);

    __syncthreads();  // drains vmcnt (stage+mask) + lgkm; next tile ready
    cur ^= 1;
  }

  // epilogue
#pragma unroll
  for (int r = 0; r < 4; r++) {
    float inv_l = 1.0f / l_run[r];
    int t = tok0 + qrow + r;
#pragma unroll
    for (int j = 0; j < 4; j++)
      o[(size_t)t * E_DIM + h * 64 + j * 16 + lm] = f2bf(oacc[j][r] * inv_l);
  }
}

extern "C" void kernel_launch(void* const* d_in, const int* in_sizes, int n_in,
                              void* d_out, int out_size, void* d_ws, size_t ws_size,
                              hipStream_t stream) {
  const float* x = (const float*)d_in[0];
  const int* mask = (const int*)d_in[1];
  const float* ln1_s = (const float*)d_in[2];
  const float* ln1_b = (const float*)d_in[3];
  const float* Wqkv = (const float*)d_in[4];
  const float* bqkv = (const float*)d_in[5];
  const float* Wo = (const float*)d_in[6];
  const float* bo = (const float*)d_in[7];
  const float* ln2_s = (const float*)d_in[8];
  const float* ln2_b = (const float*)d_in[9];
  const float* lnf_s = (const float*)d_in[10];
  const float* lnf_b = (const float*)d_in[11];
  const float* W1 = (const float*)d_in[12];
  const float* b1 = (const float*)d_in[13];
  const float* W2 = (const float*)d_in[14];
  const float* b2 = (const float*)d_in[15];

  size_t off = 0;
  auto alloc = [&](size_t bytes) {
    void* p = (char*)d_ws + off;
    off += (bytes + 255) & ~(size_t)255;
    return p;
  };
  unsigned short* WqkvT = (unsigned short*)alloc((size_t)3072 * 1024 * 2);
  unsigned short* WoT = (unsigned short*)alloc((size_t)1024 * 1024 * 2);
  unsigned short* W1T = (unsigned short*)alloc((size_t)4096 * 1024 * 2);
  unsigned short* W2T = (unsigned short*)alloc((size_t)1024 * 4096 * 2);
  unsigned short* h1 = (unsigned short*)alloc((size_t)T_TOK * E_DIM * 2);
  unsigned short* qkvb = (unsigned short*)alloc((size_t)T_TOK * 3 * E_DIM * 2);
  unsigned short* ob = (unsigned short*)alloc((size_t)T_TOK * E_DIM * 2);
  float* x2 = (float*)alloc((size_t)T_TOK * E_DIM * 4);
  unsigned short* h2 = (unsigned short*)alloc((size_t)T_TOK * E_DIM * 2);
  unsigned short* g1 = (unsigned short*)alloc((size_t)T_TOK * DFF_DIM * 2);
  float* part = (float*)alloc((size_t)4 * T_TOK * E_DIM * 4);  // 4 K-slices
  unsigned short* vtg = (unsigned short*)alloc((size_t)T_TOK * E_DIM * 2);
  const size_t PSTRIDE = (size_t)T_TOK * E_DIM;

  // weight prep
  convert_transpose<<<dim3(3072 / 32, 1024 / 32), 256, 0, stream>>>(Wqkv, WqkvT, 1024, 3072);
  convert_transpose<<<dim3(1024 / 32, 1024 / 32), 256, 0, stream>>>(Wo, WoT, 1024, 1024);
  convert_transpose<<<dim3(4096 / 32, 1024 / 32), 256, 0, stream>>>(W1, W1T, 1024, 4096);
  convert_transpose<<<dim3(1024 / 32, 4096 / 32), 256, 0, stream>>>(W2, W2T, 4096, 1024);
  // LN1
  ln_kernel<<<T_TOK, 256, 0, stream>>>(x, ln1_s, ln1_b, h1);
  // QKV (768 blocks, 3/CU)
  gemm_bt<0><<<dim3(3072 / 128, T_TOK / 128, 1), 256, 0, stream>>>(
      h1, WqkvT, bqkv, qkvb, T_TOK, 3072, 1024, 1024);
  // V transpose for attention staging
  v_transpose<<<dim3(L_SEQ / 64, N_BATCH * H_HEADS), 256, 0, stream>>>(qkvb, vtg);
  // attention
  attn_kernel<<<dim3(L_SEQ / 64, N_BATCH * H_HEADS), 256, 0, stream>>>(
      qkvb, vtg, mask, ob);
  // Wo split-K=2 (512 blocks) -> part[0],part[1]
  gemm_bt<3><<<dim3(1024 / 128, T_TOK / 128, 2), 256, 0, stream>>>(
      ob, WoT, nullptr, part, T_TOK, 1024, 1024, 512);
  // x2 = p0+p1+x+bo ; h2 = LN(LN(x2))
  ln2_fused_kernel<<<T_TOK, 256, 0, stream>>>(
      part, part + PSTRIDE, x, bo, ln2_s, ln2_b, lnf_s, lnf_b, x2, h2);
  // FF1 + gelu (1024 blocks, 4/CU)
  gemm_bt<1><<<dim3(DFF_DIM / 128, T_TOK / 128, 1), 256, 0, stream>>>(
      h2, W1T, b1, g1, T_TOK, DFF_DIM, 1024, 1024);
  // FF2 split-K=4 (1024 blocks, 4/CU) -> part[0..3]
  gemm_bt<3><<<dim3(1024 / 128, T_TOK / 128, 4), 256, 0, stream>>>(
      g1, W2T, nullptr, part, T_TOK, 1024, 4096, 1024);
  // out = p0+p1+p2+p3 + x2 + b2
  add4_kernel<<<T_TOK, 256, 0, stream>>>(
      part, part + PSTRIDE, part + 2 * PSTRIDE, part + 3 * PSTRIDE,
      x2, b2, (float*)d_out);

  (void)in_sizes; (void)n_in; (void)out_size; (void)ws_size;
}

// Round 7
// 1035.851 us; speedup vs baseline: 2.7146x; 1.0348x over previous
//
#include <hip/hip_runtime.h>
#include <math.h>

#define E_DIM 1024
#define H_HEADS 16
#define D_HEAD 64
#define DFF_DIM 4096
#define L_SEQ 2048
#define N_BATCH 2
#define T_TOK (N_BATCH * L_SEQ)

typedef __attribute__((ext_vector_type(8))) __bf16 bf16x8;
typedef __attribute__((ext_vector_type(4))) float f32x4;

__device__ __forceinline__ unsigned short f2bf(float f) {
  union { float f; unsigned int u; } v; v.f = f;
  unsigned int r = v.u + 0x7fffu + ((v.u >> 16) & 1u);
  return (unsigned short)(r >> 16);
}

// async global->LDS, 16B per lane; LDS dest is wave-uniform base + lane*16;
// global source address is PER-LANE (swizzles live on the global side).
__device__ __forceinline__ void gld16(const void* g, void* l) {
  __builtin_amdgcn_global_load_lds(
      (const __attribute__((address_space(1))) unsigned int*)g,
      (__attribute__((address_space(3))) unsigned int*)l, 16, 0, 0);
}

// ---------------- weight convert + transpose: in [K,N] f32 -> out [N,K] bf16 ----
__global__ __launch_bounds__(256) void convert_transpose(
    const float* __restrict__ in, unsigned short* __restrict__ out, int K, int N) {
  __shared__ float tile[32][33];
  int n0 = blockIdx.x * 32, k0 = blockIdx.y * 32;
  int tx = threadIdx.x & 31, ty = threadIdx.x >> 5;  // 32 x 8
#pragma unroll
  for (int i = 0; i < 32; i += 8)
    tile[ty + i][tx] = in[(size_t)(k0 + ty + i) * N + n0 + tx];
  __syncthreads();
#pragma unroll
  for (int i = 0; i < 32; i += 8)
    out[(size_t)(n0 + ty + i) * K + k0 + tx] = f2bf(tile[tx][ty + i]);
}

// ---- V transpose: qkv bf16 [T,3E] V-part -> vtg [nh=32][d=64][L] bf16 -------
__global__ __launch_bounds__(256) void v_transpose(
    const unsigned short* __restrict__ qkv, unsigned short* __restrict__ vtg) {
  __shared__ unsigned short t[64][72];
  int kb = blockIdx.x * 64;
  int nh = blockIdx.y, n = nh >> 4, h = nh & 15;
  int tid = threadIdx.x;
  int r = tid >> 3, ch = tid & 7;
  const size_t TS = 3 * E_DIM;
  const size_t voff = 2 * E_DIM + h * 64;
#pragma unroll
  for (int it = 0; it < 2; it++) {
    int row = r + it * 32;  // token within tile
    uint4 v = *(const uint4*)(qkv + (size_t)(n * L_SEQ + kb + row) * TS + voff + ch * 8);
    *(uint4*)(&t[row][ch * 8]) = v;
  }
  __syncthreads();
#pragma unroll
  for (int it = 0; it < 2; it++) {
    int d = r + it * 32;
    unsigned short tmp[8];
#pragma unroll
    for (int s = 0; s < 8; s++) tmp[s] = t[ch * 8 + s][d];
    *(uint4*)(vtg + ((size_t)nh * 64 + d) * L_SEQ + kb + ch * 8) = *(uint4*)tmp;
  }
}

// ---------------- block reduce (sum pair) over 256 threads ----------------
__device__ __forceinline__ void block_reduce2(float& a, float& b, float* sm, int tid) {
#pragma unroll
  for (int off = 32; off > 0; off >>= 1) {
    a += __shfl_down(a, off);
    b += __shfl_down(b, off);
  }
  int wid = tid >> 6;
  if ((tid & 63) == 0) { sm[wid * 2] = a; sm[wid * 2 + 1] = b; }
  __syncthreads();
  a = sm[0] + sm[2] + sm[4] + sm[6];
  b = sm[1] + sm[3] + sm[5] + sm[7];
}

// ---------------- LN1: x f32 [T,E] -> bf16 [T,E] ----------------
__global__ __launch_bounds__(256) void ln_kernel(
    const float* __restrict__ x, const float* __restrict__ s,
    const float* __restrict__ b, unsigned short* __restrict__ out) {
  int row = blockIdx.x, tid = threadIdx.x;
  __shared__ float sm[8];
  float4 v = ((const float4*)(x + (size_t)row * E_DIM))[tid];
  float sum = v.x + v.y + v.z + v.w;
  float sq = v.x * v.x + v.y * v.y + v.z * v.z + v.w * v.w;
  block_reduce2(sum, sq, sm, tid);
  float mu = sum * (1.0f / E_DIM);
  float var = sq * (1.0f / E_DIM) - mu * mu;
  float rs = rsqrtf(var + 1e-5f);
  float4 sv = ((const float4*)s)[tid];
  float4 bv = ((const float4*)b)[tid];
  ushort4 o4;
  o4.x = f2bf((v.x - mu) * rs * sv.x + bv.x);
  o4.y = f2bf((v.y - mu) * rs * sv.y + bv.y);
  o4.z = f2bf((v.z - mu) * rs * sv.z + bv.z);
  o4.w = f2bf((v.w - mu) * rs * sv.w + bv.w);
  ((ushort4*)(out + (size_t)row * E_DIM))[tid] = o4;
}

// ------ fused: x2 = p0+p1+x+bo ; h2 = LN(LN(x2,s2,b2),sf,bf) -> bf16 --------
__global__ __launch_bounds__(256) void ln2_fused_kernel(
    const float* __restrict__ p0, const float* __restrict__ p1,
    const float* __restrict__ x, const float* __restrict__ bo,
    const float* __restrict__ s2, const float* __restrict__ b2,
    const float* __restrict__ sf, const float* __restrict__ bf_,
    float* __restrict__ x2, unsigned short* __restrict__ out) {
  int row = blockIdx.x, tid = threadIdx.x;
  __shared__ float sm[8];
  float4 a0 = ((const float4*)(p0 + (size_t)row * E_DIM))[tid];
  float4 a1 = ((const float4*)(p1 + (size_t)row * E_DIM))[tid];
  float4 xv = ((const float4*)(x + (size_t)row * E_DIM))[tid];
  float4 bov = ((const float4*)bo)[tid];
  float4 v;
  v.x = a0.x + a1.x + xv.x + bov.x;
  v.y = a0.y + a1.y + xv.y + bov.y;
  v.z = a0.z + a1.z + xv.z + bov.z;
  v.w = a0.w + a1.w + xv.w + bov.w;
  ((float4*)(x2 + (size_t)row * E_DIM))[tid] = v;
  float sum = v.x + v.y + v.z + v.w;
  float sq = v.x * v.x + v.y * v.y + v.z * v.z + v.w * v.w;
  block_reduce2(sum, sq, sm, tid);
  float mu = sum * (1.0f / E_DIM);
  float rs = rsqrtf(sq * (1.0f / E_DIM) - mu * mu + 1e-5f);
  float4 s2v = ((const float4*)s2)[tid];
  float4 b2v = ((const float4*)b2)[tid];
  float y0 = (v.x - mu) * rs * s2v.x + b2v.x;
  float y1 = (v.y - mu) * rs * s2v.y + b2v.y;
  float y2 = (v.z - mu) * rs * s2v.z + b2v.z;
  float y3 = (v.w - mu) * rs * s2v.w + b2v.w;
  float sum2 = y0 + y1 + y2 + y3;
  float sq2 = y0 * y0 + y1 * y1 + y2 * y2 + y3 * y3;
  __syncthreads();
  block_reduce2(sum2, sq2, sm, tid);
  float mu2 = sum2 * (1.0f / E_DIM);
  float rs2 = rsqrtf(sq2 * (1.0f / E_DIM) - mu2 * mu2 + 1e-5f);
  float4 sfv = ((const float4*)sf)[tid];
  float4 bfv = ((const float4*)bf_)[tid];
  ushort4 o4;
  o4.x = f2bf((y0 - mu2) * rs2 * sfv.x + bfv.x);
  o4.y = f2bf((y1 - mu2) * rs2 * sfv.y + bfv.y);
  o4.z = f2bf((y2 - mu2) * rs2 * sfv.z + bfv.z);
  o4.w = f2bf((y3 - mu2) * rs2 * sfv.w + bfv.w);
  ((ushort4*)(out + (size_t)row * E_DIM))[tid] = o4;
}

// ---- FF2 final reduce: out = p0+p1+p2+p3 + resid + bias (all f32) ----------
__global__ __launch_bounds__(256) void add4_kernel(
    const float* __restrict__ p0, const float* __restrict__ p1,
    const float* __restrict__ p2, const float* __restrict__ p3,
    const float* __restrict__ resid, const float* __restrict__ bias,
    float* __restrict__ out) {
  int row = blockIdx.x, tid = threadIdx.x;
  size_t base = (size_t)row * E_DIM;
  float4 a0 = ((const float4*)(p0 + base))[tid];
  float4 a1 = ((const float4*)(p1 + base))[tid];
  float4 a2 = ((const float4*)(p2 + base))[tid];
  float4 a3 = ((const float4*)(p3 + base))[tid];
  float4 rv = ((const float4*)(resid + base))[tid];
  float4 bv = ((const float4*)bias)[tid];
  float4 o;
  o.x = a0.x + a1.x + a2.x + a3.x + rv.x + bv.x;
  o.y = a0.y + a1.y + a2.y + a3.y + rv.y + bv.y;
  o.z = a0.z + a1.z + a2.z + a3.z + rv.z + bv.z;
  o.w = a0.w + a1.w + a2.w + a3.w + rv.w + bv.w;
  ((float4*)(out + base))[tid] = o;
}

// ---------------- GEMM (m97 structure): C[M,N] = A[M,K](bf16) * Bt[N,K]^T ----
// EPI 0: store bf16 (+bias); 1: gelu->bf16 (+bias); 3: f32 partial (split-K).
template <int EPI>
__global__ __launch_bounds__(256) void gemm_bt(
    const unsigned short* __restrict__ A, const unsigned short* __restrict__ Bt,
    const float* __restrict__ bias, void* __restrict__ outp,
    int M, int N, int K, int Ks) {
  __shared__ unsigned short As[128 * 32];
  __shared__ unsigned short Bs[128 * 32];
  int tid = threadIdx.x;
  int lane = tid & 63, wave = tid >> 6;
  int m0 = blockIdx.y * 128, n0 = blockIdx.x * 128;
  int kz = blockIdx.z * Ks;
  int wm = (wave & 1) * 64, wn = (wave >> 1) * 64;
  int lm = lane & 15, lq = lane >> 4;
  int srow = wave * 32 + (lane >> 2);
  int scol = (lane & 3) * 8;
  const unsigned short* Ag = A + (size_t)(m0 + srow) * K + scol;
  const unsigned short* Bg = Bt + (size_t)(n0 + srow) * K + scol;
  unsigned short* AsW = As + wave * 1024;
  unsigned short* BsW = Bs + wave * 1024;
  f32x4 acc[4][4] = {};
  for (int k0 = kz; k0 < kz + Ks; k0 += 32) {
    __syncthreads();
    gld16(Ag + k0, AsW);
    gld16(Ag + (size_t)16 * K + k0, AsW + 512);
    gld16(Bg + k0, BsW);
    gld16(Bg + (size_t)16 * K + k0, BsW + 512);
    __syncthreads();
    bf16x8 a[4], b[4];
#pragma unroll
    for (int i = 0; i < 4; i++)
      a[i] = *(const bf16x8*)(As + (wm + i * 16 + lm) * 32 + lq * 8);
#pragma unroll
    for (int j = 0; j < 4; j++)
      b[j] = *(const bf16x8*)(Bs + (wn + j * 16 + lm) * 32 + lq * 8);
#pragma unroll
    for (int i = 0; i < 4; i++)
#pragma unroll
      for (int j = 0; j < 4; j++)
        acc[i][j] = __builtin_amdgcn_mfma_f32_16x16x32_bf16(a[i], b[j], acc[i][j], 0, 0, 0);
  }
  float* pout = (EPI == 3) ? ((float*)outp + (size_t)blockIdx.z * M * N) : nullptr;
#pragma unroll
  for (int i = 0; i < 4; i++)
#pragma unroll
    for (int j = 0; j < 4; j++) {
      int row = m0 + wm + i * 16 + lq * 4;
      int col = n0 + wn + j * 16 + lm;
      float bcol = (EPI == 3) ? 0.0f : bias[col];
#pragma unroll
      for (int r = 0; r < 4; r++) {
        float v = acc[i][j][r] + bcol;
        size_t idx = (size_t)(row + r) * N + col;
        if (EPI == 0) {
          ((unsigned short*)outp)[idx] = f2bf(v);
        } else if (EPI == 1) {
          float g = 0.5f * v * (1.0f + erff(v * 0.70710678118f));
          ((unsigned short*)outp)[idx] = f2bf(g);
        } else {
          pout[idx] = v;
        }
      }
    }
}

// ---------------- flash attention v4: swapped QK^T, in-register P ------------
// mfma(K,Q) gives lane one full q-row (q=lm): S[key=16nt+4lq+r][q=lm].
// Softmax = in-lane reduce over 16 + 2 shfl_xor; P packed to bf16 in regs and
// redistributed to the PV A-fragment layout with 16 bpermutes — no P LDS, no
// lgkm drain. K/V staged by gld16 into swizzled double-buffered tiles (32 KB).
__global__ __launch_bounds__(256) void attn_kernel(
    const unsigned short* __restrict__ qkv,
    const unsigned short* __restrict__ vtg,
    const int* __restrict__ mask,
    unsigned short* __restrict__ o) {
  const int bq = blockIdx.x;   // q tile (64 rows)
  const int nh = blockIdx.y;   // n*H + h
  const int h = nh & 15;
  const int tid = threadIdx.x, lane = tid & 63, wave = tid >> 6;
  const int lm = lane & 15, lq = lane >> 4, lm7 = lm & 7;

  __shared__ unsigned short Kb[2][64 * 64];   // [key][chunk ^ (key&7)]
  __shared__ unsigned short Vb[2][64 * 64];   // [d][kchunk ^ (d&7)]

  const int q_base = bq * 64;
  const int tok0 = (nh >> 4) * L_SEQ;
  const int qoff = h * 64, koff = E_DIM + h * 64;
  const int* mbase = mask + (size_t)nh * L_SEQ * L_SEQ;
  const size_t TS = 3 * E_DIM;

  // Q fragment: Q[q = q_base + wave*16 + lm][d = lq*8.. , +32]
  bf16x8 qf[2];
  {
    int t = tok0 + q_base + wave * 16 + lm;
    const unsigned short* qr = qkv + (size_t)t * TS + qoff + lq * 8;
    qf[0] = *(const bf16x8*)(qr);
    qf[1] = *(const bf16x8*)(qr + 32);
  }

  const int qml = q_base + wave * 16 + lm;      // this lane's q row (S/softmax)
  const int qro = q_base + wave * 16 + lq * 4;  // oacc q base (epilogue)

  // staging lane geometry (global-side swizzle, LDS linear)
  const int lrow = lane >> 3;
  const int xch = ((lane & 7) ^ lrow) * 8;
  const unsigned short* kgb = qkv + koff + xch;
  const unsigned short* vgb = vtg + (size_t)nh * 64 * L_SEQ + xch;

  auto STAGE = [&](int buf, int kt) {
    int kb = kt * 64;
#pragma unroll
    for (int cc = 0; cc < 2; cc++) {
      int c = wave * 2 + cc;
      int row = c * 8 + lrow;
      gld16(kgb + (size_t)(tok0 + kb + row) * TS, Kb[buf] + c * 512);
      gld16(vgb + (size_t)row * L_SEQ + kb, Vb[buf] + c * 512);
    }
  };

  // mask regs: mrg[nt] = mask[qml][kb + nt*16 + lq*4 .. +3]
  int4 mrg[4];
  auto load_m = [&](int kt) {
    const int* mp = mbase + (size_t)qml * L_SEQ + kt * 64 + lq * 4;
#pragma unroll
    for (int nt = 0; nt < 4; nt++)
      mrg[nt] = *(const int4*)(mp + nt * 16);
  };

  // P-redistribution source lanes (constant): frag needs k=8*lq+j from
  // source lanes lq_s = {(2lq)&3, +1}, nt selected by lq>>1.
  const int s0 = (2 * lq) & 3;
  const int srcA = lm + (s0 << 4);
  const int srcB = lm + ((s0 + 1) << 4);
  const int ntsel = lq >> 1;

  float m_run = -1e30f, l_run = 0.0f;
  f32x4 oacc[4] = {};

  // prologue
  STAGE(0, 0);
  load_m(0);
  __syncthreads();  // drains vmcnt -> tile 0 staged

  int cur = 0;
  const int NT = L_SEQ / 64;
  for (int kt = 0; kt < NT; kt++) {
    if (kt + 1 < NT) STAGE(cur ^ 1, kt + 1);

    // ---- S = mfma(K, Q): lane holds S[key=16nt+4lq+r][q=lm] ----
    f32x4 s[4];
    __builtin_amdgcn_s_setprio(1);
#pragma unroll
    for (int nt = 0; nt < 4; nt++) {
      int kidx = (nt * 16 + lm) * 64 + ((lq ^ lm7) << 3);
      bf16x8 kb0 = *(const bf16x8*)(Kb[cur] + kidx);        // K[key][d=8lq..]
      bf16x8 kb1 = *(const bf16x8*)(Kb[cur] + (kidx ^ 32)); // K[key][d=8lq+32..]
      f32x4 acc = {};
      acc = __builtin_amdgcn_mfma_f32_16x16x32_bf16(kb0, qf[0], acc, 0, 0, 0);
      acc = __builtin_amdgcn_mfma_f32_16x16x32_bf16(kb1, qf[1], acc, 0, 0, 0);
      s[nt] = acc;
    }
    __builtin_amdgcn_s_setprio(0);

    // ---- mask (prefetched int4 regs) ----
#pragma unroll
    for (int nt = 0; nt < 4; nt++) {
      s[nt][0] = mrg[nt].x ? -1e30f : s[nt][0] * 0.125f;
      s[nt][1] = mrg[nt].y ? -1e30f : s[nt][1] * 0.125f;
      s[nt][2] = mrg[nt].z ? -1e30f : s[nt][2] * 0.125f;
      s[nt][3] = mrg[nt].w ? -1e30f : s[nt][3] * 0.125f;
    }
    load_m((kt + 1 < NT) ? kt + 1 : kt);  // prefetch next mask

    // ---- row max: in-lane 16 + xor over lanes ^16, ^32 ----
    float mx = fmaxf(fmaxf(s[0][0], s[0][1]), fmaxf(s[0][2], s[0][3]));
#pragma unroll
    for (int nt = 1; nt < 4; nt++)
      mx = fmaxf(mx, fmaxf(fmaxf(s[nt][0], s[nt][1]), fmaxf(s[nt][2], s[nt][3])));
    mx = fmaxf(mx, __shfl_xor(mx, 16));
    mx = fmaxf(mx, __shfl_xor(mx, 32));
    float mn = fmaxf(m_run, mx);
    float alpha = __expf(m_run - mn);
    m_run = mn;

    // ---- exp + pack to bf16 pairs (pk[nt] = {(p0,p1),(p2,p3)}) ----
    unsigned int pk[4][2];
    float rs = 0.0f;
#pragma unroll
    for (int nt = 0; nt < 4; nt++) {
      float p0 = __expf(s[nt][0] - mn), p1 = __expf(s[nt][1] - mn);
      float p2 = __expf(s[nt][2] - mn), p3 = __expf(s[nt][3] - mn);
      rs += (p0 + p1) + (p2 + p3);
      pk[nt][0] = (unsigned int)f2bf(p0) | ((unsigned int)f2bf(p1) << 16);
      pk[nt][1] = (unsigned int)f2bf(p2) | ((unsigned int)f2bf(p3) << 16);
    }
    rs += __shfl_xor(rs, 16);
    rs += __shfl_xor(rs, 32);
    l_run = l_run * alpha + rs;

    // ---- redistribute P -> A-frag layout P[q=lm][k=8lq+j] via bpermute ----
    union PF { unsigned int w[4]; bf16x8 v; } pf0, pf1;
    {
      unsigned int a00 = __shfl((int)pk[0][0], srcA), a01 = __shfl((int)pk[0][1], srcA);
      unsigned int a10 = __shfl((int)pk[1][0], srcA), a11 = __shfl((int)pk[1][1], srcA);
      unsigned int b00 = __shfl((int)pk[0][0], srcB), b01 = __shfl((int)pk[0][1], srcB);
      unsigned int b10 = __shfl((int)pk[1][0], srcB), b11 = __shfl((int)pk[1][1], srcB);
      pf0.w[0] = ntsel ? a10 : a00;
      pf0.w[1] = ntsel ? a11 : a01;
      pf0.w[2] = ntsel ? b10 : b00;
      pf0.w[3] = ntsel ? b11 : b01;
      unsigned int c00 = __shfl((int)pk[2][0], srcA), c01 = __shfl((int)pk[2][1], srcA);
      unsigned int c10 = __shfl((int)pk[3][0], srcA), c11 = __shfl((int)pk[3][1], srcA);
      unsigned int d00 = __shfl((int)pk[2][0], srcB), d01 = __shfl((int)pk[2][1], srcB);
      unsigned int d10 = __shfl((int)pk[3][0], srcB), d11 = __shfl((int)pk[3][1], srcB);
      pf1.w[0] = ntsel ? c10 : c00;
      pf1.w[1] = ntsel ? c11 : c01;
      pf1.w[2] = ntsel ? d10 : d00;
      pf1.w[3] = ntsel ? d11 : d01;
    }

    // ---- rescale oacc: alpha for q = lq*4+r lives at lane lq*4+r ----
    float af[4];
#pragma unroll
    for (int r = 0; r < 4; r++) af[r] = __shfl(alpha, qro - q_base - wave * 16 + r);
#pragma unroll
    for (int j = 0; j < 4; j++)
#pragma unroll
      for (int r = 0; r < 4; r++) oacc[j][r] *= af[r];

    // ---- O += P V ----
    __builtin_amdgcn_s_setprio(1);
#pragma unroll
    for (int c = 0; c < 2; c++) {
      bf16x8 pa = c ? pf1.v : pf0.v;
      int pc = (((c << 2) | lq) ^ lm7) << 3;  // Vt swizzle: retrieves k=c*32+8lq..
#pragma unroll
      for (int j = 0; j < 4; j++) {
        bf16x8 vb = *(const bf16x8*)(Vb[cur] + (j * 16 + lm) * 64 + pc);
        oacc[j] = __builtin_amdgcn_mfma_f32_16x16x32_bf16(pa, vb, oacc[j], 0, 0, 0);
      }
    }
    __builtin_amdgcn_s_setprio(0);

    __syncthreads();  // drains vmcnt; next tile staged
    cur ^= 1;
  }

  // epilogue: 1/l for q=lq*4+r lives at lane lq*4+r
#pragma unroll
  for (int r = 0; r < 4; r++) {
    float lr = __shfl(l_run, (lq * 4 + r));
    float inv_l = 1.0f / lr;
    int t = tok0 + qro + r;
#pragma unroll
    for (int j = 0; j < 4; j++)
      o[(size_t)t * E_DIM + h * 64 + j * 16 + lm] = f2bf(oacc[j][r] * inv_l);
  }
}

extern "C" void kernel_launch(void* const* d_in, const int* in_sizes, int n_in,
                              void* d_out, int out_size, void* d_ws, size_t ws_size,
                              hipStream_t stream) {
  const float* x = (const float*)d_in[0];
  const int* mask = (const int*)d_in[1];
  const float* ln1_s = (const float*)d_in[2];
  const float* ln1_b = (const float*)d_in[3];
  const float* Wqkv = (const float*)d_in[4];
  const float* bqkv = (const float*)d_in[5];
  const float* Wo = (const float*)d_in[6];
  const float* bo = (const float*)d_in[7];
  const float* ln2_s = (const float*)d_in[8];
  const float* ln2_b = (const float*)d_in[9];
  const float* lnf_s = (const float*)d_in[10];
  const float* lnf_b = (const float*)d_in[11];
  const float* W1 = (const float*)d_in[12];
  const float* b1 = (const float*)d_in[13];
  const float* W2 = (const float*)d_in[14];
  const float* b2 = (const float*)d_in[15];

  size_t off = 0;
  auto alloc = [&](size_t bytes) {
    void* p = (char*)d_ws + off;
    off += (bytes + 255) & ~(size_t)255;
    return p;
  };
  unsigned short* WqkvT = (unsigned short*)alloc((size_t)3072 * 1024 * 2);
  unsigned short* WoT = (unsigned short*)alloc((size_t)1024 * 1024 * 2);
  unsigned short* W1T = (unsigned short*)alloc((size_t)4096 * 1024 * 2);
  unsigned short* W2T = (unsigned short*)alloc((size_t)1024 * 4096 * 2);
  unsigned short* h1 = (unsigned short*)alloc((size_t)T_TOK * E_DIM * 2);
  unsigned short* qkvb = (unsigned short*)alloc((size_t)T_TOK * 3 * E_DIM * 2);
  unsigned short* ob = (unsigned short*)alloc((size_t)T_TOK * E_DIM * 2);
  float* x2 = (float*)alloc((size_t)T_TOK * E_DIM * 4);
  unsigned short* h2 = (unsigned short*)alloc((size_t)T_TOK * E_DIM * 2);
  unsigned short* g1 = (unsigned short*)alloc((size_t)T_TOK * DFF_DIM * 2);
  float* part = (float*)alloc((size_t)4 * T_TOK * E_DIM * 4);  // 4 K-slices
  unsigned short* vtg = (unsigned short*)alloc((size_t)T_TOK * E_DIM * 2);
  const size_t PSTRIDE = (size_t)T_TOK * E_DIM;

  // weight prep
  convert_transpose<<<dim3(3072 / 32, 1024 / 32), 256, 0, stream>>>(Wqkv, WqkvT, 1024, 3072);
  convert_transpose<<<dim3(1024 / 32, 1024 / 32), 256, 0, stream>>>(Wo, WoT, 1024, 1024);
  convert_transpose<<<dim3(4096 / 32, 1024 / 32), 256, 0, stream>>>(W1, W1T, 1024, 4096);
  convert_transpose<<<dim3(1024 / 32, 4096 / 32), 256, 0, stream>>>(W2, W2T, 4096, 1024);
  // LN1
  ln_kernel<<<T_TOK, 256, 0, stream>>>(x, ln1_s, ln1_b, h1);
  // QKV (768 blocks, 3/CU)
  gemm_bt<0><<<dim3(3072 / 128, T_TOK / 128, 1), 256, 0, stream>>>(
      h1, WqkvT, bqkv, qkvb, T_TOK, 3072, 1024, 1024);
  // V transpose for attention staging
  v_transpose<<<dim3(L_SEQ / 64, N_BATCH * H_HEADS), 256, 0, stream>>>(qkvb, vtg);
  // attention
  attn_kernel<<<dim3(L_SEQ / 64, N_BATCH * H_HEADS), 256, 0, stream>>>(
      qkvb, vtg, mask, ob);
  // Wo split-K=2 (512 blocks) -> part[0],part[1]
  gemm_bt<3><<<dim3(1024 / 128, T_TOK / 128, 2), 256, 0, stream>>>(
      ob, WoT, nullptr, part, T_TOK, 1024, 1024, 512);
  // x2 = p0+p1+x+bo ; h2 = LN(LN(x2))
  ln2_fused_kernel<<<T_TOK, 256, 0, stream>>>(
      part, part + PSTRIDE, x, bo, ln2_s, ln2_b, lnf_s, lnf_b, x2, h2);
  // FF1 + gelu (1024 blocks, 4/CU)
  gemm_bt<1><<<dim3(DFF_DIM / 128, T_TOK / 128, 1), 256, 0, stream>>>(
      h2, W1T, b1, g1, T_TOK, DFF_DIM, 1024, 1024);
  // FF2 split-K=4 (1024 blocks, 4/CU) -> part[0..3]
  gemm_bt<3><<<dim3(1024 / 128, T_TOK / 128, 4), 256, 0, stream>>>(
      g1, W2T, nullptr, part, T_TOK, 1024, 4096, 1024);
  // out = p0+p1+p2+p3 + x2 + b2
  add4_kernel<<<T_TOK, 256, 0, stream>>>(
      part, part + PSTRIDE, part + 2 * PSTRIDE, part + 3 * PSTRIDE,
      x2, b2, (float*)d_out);

  (void)in_sizes; (void)n_in; (void)out_size; (void)ws_size;
}